// Round 8
// baseline (186.661 us; speedup 1.0000x reference)
//
#include <hip/hip_runtime.h>
#include <hip/hip_bf16.h>

typedef __hip_bfloat16 bf16;
typedef short bf16x8 __attribute__((ext_vector_type(8)));
typedef float f32x4 __attribute__((ext_vector_type(4)));

#define HT 16384   // bf16 half-tile bytes: 128 rows x 64 cols

__device__ __forceinline__ void gload16(const void* g, void* l) {
    __builtin_amdgcn_global_load_lds(
        (const __attribute__((address_space(1))) void*)g,
        (__attribute__((address_space(3))) void*)l, 16, 0, 0);
}

// Stage one 128x64 bf16 half-tile into LDS slot slotIdx (16 KiB units).
// Linear LDS dest; source pre-swizzled with involution chunk ^= row&7.
__device__ __forceinline__ void stage_half(char* lds, const bf16* src, int ld,
                                           int rowbase, int k0, int slotIdx,
                                           int tid)
{
    char* dst = lds + (size_t)slotIdx * HT + tid * 16;
    const int sub = tid >> 3;
    const int cb  = ((tid & 7) ^ (sub & 7)) << 4;
    #pragma unroll
    for (int p = 0; p < 2; ++p) {
        const int row = p * 64 + sub;
        const char* g = (const char*)(src + (size_t)(rowbase + row) * ld + k0) + cb;
        gload16(g, dst + p * 8192);
    }
}

// read one MFMA A/B fragment (8 bf16 = 16B) with the read-side swizzle
__device__ __forceinline__ bf16x8 ldsfrag(const char* lds, int slotIdx,
                                          int row, int ks, int cb0)
{
    return *(const bf16x8*)(lds + (size_t)slotIdx * HT
                            + row * 128 + (cb0 ^ (ks << 6)));
}

__device__ __forceinline__ float bf2f(short s) {
    union { float f; unsigned u; } c;
    c.u = ((unsigned)(unsigned short)s) << 16;
    return c.f;
}

// ====== projection: BM=256 BN=128, 8 waves 4Mx2N (wave 64x64), 96 KiB ======
// q,k rows -> proj row-major; v rows -> vpT transposed (saves transpose_vp).
__launch_bounds__(512, 2)
__global__ void proj_bn128(const bf16* __restrict__ A, const bf16* __restrict__ B,
                           bf16* __restrict__ C, bf16* __restrict__ vpT)
{
    extern __shared__ char lds[];
    const int orig = blockIdx.y * 8 + blockIdx.x;      // 768 blocks
    const int wk2 = (orig & 7) * 96 + (orig >> 3);     // bijective, 96/XCD
    const int bi = wk2 >> 3, bj = wk2 & 7;             // bi 0..95, bj 0..7
    const int brow = bi * 256, bcol = bj * 128;

    const int tid  = threadIdx.x;
    const int lane = tid & 63;
    const int w    = tid >> 6;
    const int wm   = w >> 1, wn = w & 1;
    const int fr   = lane & 15, fq = lane >> 4;
    const int cb0  = ((fr & 7) ^ fq) << 4;
    const int slotA = wm >> 1;
    const int rA    = (wm & 1) * 64;
    const int rB    = wn * 64;
    const int NT    = 16;                              // K=1024/64

    f32x4 acc[4][4] = {};
    bf16x8 af[4][2], bv[4][2];

    stage_half(lds, B, 1024, bcol,       0, 2, tid);
    stage_half(lds, A, 1024, brow,       0, 0, tid);
    stage_half(lds, A, 1024, brow + 128, 0, 1, tid);
    stage_half(lds, B, 1024, bcol,      64, 5, tid);
    asm volatile("s_waitcnt vmcnt(2)" ::: "memory");
    __builtin_amdgcn_s_barrier();

#define QUAD2(m0, n0)                                                         \
    _Pragma("unroll") for (int dm = 0; dm < 2; ++dm)                          \
    _Pragma("unroll") for (int dn = 0; dn < 2; ++dn)                          \
    _Pragma("unroll") for (int ks = 0; ks < 2; ++ks)                          \
        acc[(m0)+dm][(n0)+dn] = __builtin_amdgcn_mfma_f32_16x16x32_bf16(      \
            af[(m0)+dm][ks], bv[(n0)+dn][ks], acc[(m0)+dm][(n0)+dn], 0, 0, 0);

    for (int t = 0; t < NT; ++t) {
        const int buf = t & 1, nbuf = buf ^ 1;
        const int k1 = min(t + 1, NT - 1) << 6;
        const int k2 = min(t + 2, NT - 1) << 6;

        #pragma unroll
        for (int m = 0; m < 2; ++m)
            #pragma unroll
            for (int ks = 0; ks < 2; ++ks)
                af[m][ks] = ldsfrag(lds, buf * 3 + slotA, rA + m * 16 + fr, ks, cb0);
        #pragma unroll
        for (int n = 0; n < 2; ++n)
            #pragma unroll
            for (int ks = 0; ks < 2; ++ks)
                bv[n][ks] = ldsfrag(lds, buf * 3 + 2, rB + n * 16 + fr, ks, cb0);
        stage_half(lds, A, 1024, brow, k1, nbuf * 3 + 0, tid);
        __builtin_amdgcn_s_barrier();
        __builtin_amdgcn_s_setprio(1);
        QUAD2(0, 0)
        __builtin_amdgcn_s_setprio(0);
        __builtin_amdgcn_s_barrier();

        #pragma unroll
        for (int n = 2; n < 4; ++n)
            #pragma unroll
            for (int ks = 0; ks < 2; ++ks)
                bv[n][ks] = ldsfrag(lds, buf * 3 + 2, rB + n * 16 + fr, ks, cb0);
        stage_half(lds, A, 1024, brow + 128, k1, nbuf * 3 + 1, tid);
        __builtin_amdgcn_s_barrier();
        __builtin_amdgcn_s_setprio(1);
        QUAD2(0, 2)
        __builtin_amdgcn_s_setprio(0);
        __builtin_amdgcn_s_barrier();

        #pragma unroll
        for (int m = 2; m < 4; ++m)
            #pragma unroll
            for (int ks = 0; ks < 2; ++ks)
                af[m][ks] = ldsfrag(lds, buf * 3 + slotA, rA + m * 16 + fr, ks, cb0);
        stage_half(lds, B, 1024, bcol, k2, buf * 3 + 2, tid);
        __builtin_amdgcn_s_barrier();
        __builtin_amdgcn_s_setprio(1);
        QUAD2(2, 2)
        __builtin_amdgcn_s_setprio(0);
        __builtin_amdgcn_s_barrier();

        __builtin_amdgcn_s_setprio(1);
        QUAD2(2, 0)
        __builtin_amdgcn_s_setprio(0);
        asm volatile("s_waitcnt vmcnt(2)" ::: "memory");
        __builtin_amdgcn_s_barrier();
    }
#undef QUAD2

    if (brow < 16384) {
        #pragma unroll
        for (int mf = 0; mf < 4; ++mf) {
            const int r0 = brow + wm * 64 + mf * 16 + fq * 4;
            #pragma unroll
            for (int nf = 0; nf < 4; ++nf) {
                const int c = bcol + wn * 64 + nf * 16 + fr;
                #pragma unroll
                for (int j = 0; j < 4; ++j)
                    C[(size_t)(r0 + j) * 1024 + c] = __float2bfloat16(acc[mf][nf][j]);
            }
        }
    } else {
        // v rows: store transposed into vpT[b][c][s]
        const int bb = (brow - 16384) >> 11;
        bf16* vt = vpT + (size_t)bb * 1024 * 2048;
        #pragma unroll
        for (int mf = 0; mf < 4; ++mf) {
            const int r0 = brow + wm * 64 + mf * 16 + fq * 4;
            const int s0 = (r0 - 16384) & 2047;
            #pragma unroll
            for (int nf = 0; nf < 4; ++nf) {
                const int c = bcol + wn * 64 + nf * 16 + fr;
                union { short h[4]; short4 v4; } o;
                #pragma unroll
                for (int j = 0; j < 4; ++j) {
                    bf16 hh = __float2bfloat16(acc[mf][nf][j]);
                    o.h[j] = *(short*)&hh;
                }
                *(short4*)(vt + (size_t)c * 2048 + s0) = o.v4;
            }
        }
    }
}

// ====== 128x128 split-K engine: 8 waves 2Mx2Nx2K (wave 64x64 partial) ======
// LDS: A slots 0,1,2 (rotation) + B slots 3,4 (dbuf) = 80 KiB. After loop,
// wk=1 waves dump acc to LDS (16KB/pair), wk=0 waves merge + epilogue.
// MODE 1: Cb = scale*(A@B^T) bf16.  MODE 2: Cf = A@B^T + Res f32.
template<int MODE>
__device__ __forceinline__ void tile128(char* lds, const bf16* A, const bf16* B,
                                        bf16* Cb, float* Cf, const bf16* Res,
                                        int lda, int ldb, int ldcb,
                                        int brow, int bcol, int NT, float scale,
                                        int tid)
{
    const int lane = tid & 63;
    const int w    = tid >> 6;
    const int wkk  = w & 1;                 // K-slice 0/1
    const int wn   = (w >> 1) & 1;
    const int wm   = w >> 2;
    const int fr   = lane & 15, fq = lane >> 4;
    const int cb0  = ((fr & 7) ^ fq) << 4;

    f32x4 acc[4][4] = {};
    bf16x8 af[4], bv[4];

    stage_half(lds, A, lda, brow, 0,  0, tid);
    stage_half(lds, B, ldb, bcol, 0,  3, tid);
    stage_half(lds, A, lda, brow, 64, 1, tid);
    stage_half(lds, B, ldb, bcol, 64, 4, tid);
    asm volatile("s_waitcnt vmcnt(4)" ::: "memory");
    __builtin_amdgcn_s_barrier();

    for (int t = 0; t < NT; ++t) {
        const int aslot = t % 3, bslot = 3 + (t & 1);
        const int k2 = min(t + 2, NT - 1) << 6;

        // ph0: read ALL frags (A 4 + B 4, own K-slice); stage A(t+2)
        #pragma unroll
        for (int m = 0; m < 4; ++m)
            af[m] = ldsfrag(lds, aslot, wm * 64 + m * 16 + fr, wkk, cb0);
        #pragma unroll
        for (int n = 0; n < 4; ++n)
            bv[n] = ldsfrag(lds, bslot, wn * 64 + n * 16 + fr, wkk, cb0);
        stage_half(lds, A, lda, brow, k2, (t + 2) % 3, tid);
        __builtin_amdgcn_s_barrier();
        __builtin_amdgcn_s_setprio(1);
        #pragma unroll
        for (int m = 0; m < 4; ++m)
            #pragma unroll
            for (int n = 0; n < 2; ++n)
                acc[m][n] = __builtin_amdgcn_mfma_f32_16x16x32_bf16(
                    af[m], bv[n], acc[m][n], 0, 0, 0);
        __builtin_amdgcn_s_setprio(0);
        __builtin_amdgcn_s_barrier();

        // ph1: no LDS reads; stage B(t+2)
        stage_half(lds, B, ldb, bcol, k2, bslot, tid);
        __builtin_amdgcn_s_barrier();
        __builtin_amdgcn_s_setprio(1);
        #pragma unroll
        for (int m = 0; m < 4; ++m)
            #pragma unroll
            for (int n = 2; n < 4; ++n)
                acc[m][n] = __builtin_amdgcn_mfma_f32_16x16x32_bf16(
                    af[m], bv[n], acc[m][n], 0, 0, 0);
        __builtin_amdgcn_s_setprio(0);
        asm volatile("s_waitcnt vmcnt(4)" ::: "memory");
        __builtin_amdgcn_s_barrier();
    }

    // drain in-flight dummy stages before reusing LDS for the merge
    asm volatile("s_waitcnt vmcnt(0)" ::: "memory");
    __builtin_amdgcn_s_barrier();

    char* mb = lds + (size_t)(wm * 2 + wn) * 16384 + lane * 16;
    if (wkk == 1) {
        #pragma unroll
        for (int m = 0; m < 4; ++m)
            #pragma unroll
            for (int n = 0; n < 4; ++n)
                *(f32x4*)(mb + (m * 4 + n) * 1024) = acc[m][n];
    }
    asm volatile("s_waitcnt lgkmcnt(0)" ::: "memory");
    __builtin_amdgcn_s_barrier();

    if (wkk == 0) {
        #pragma unroll
        for (int m = 0; m < 4; ++m)
            #pragma unroll
            for (int n = 0; n < 4; ++n) {
                f32x4 o = *(const f32x4*)(mb + (m * 4 + n) * 1024);
                acc[m][n] += o;
            }
        #pragma unroll
        for (int mf = 0; mf < 4; ++mf) {
            const int r0 = brow + wm * 64 + mf * 16 + fq * 4;
            #pragma unroll
            for (int nf = 0; nf < 4; ++nf) {
                const int c = bcol + wn * 64 + nf * 16 + fr;
                #pragma unroll
                for (int j = 0; j < 4; ++j) {
                    if (MODE == 1)
                        Cb[(size_t)(r0 + j) * ldcb + c] =
                            __float2bfloat16(acc[mf][nf][j] * scale);
                    else
                        Cf[(size_t)(r0 + j) * ldcb + c] = acc[mf][nf][j] +
                            __bfloat162float(Res[(size_t)(r0 + j) * ldcb + c]);
                }
            }
        }
    }
}

// scores: triangular grid, per batch 136 tiles of 128x128; P = qp@kp^T * 1/32
__launch_bounds__(512, 4)
__global__ void scores128(const bf16* __restrict__ qp, const bf16* __restrict__ kp,
                          bf16* __restrict__ P)
{
    extern __shared__ char lds[];
    const int j = blockIdx.x;                     // 0..135
    int bi = (int)((__fsqrt_rn(8.0f * j + 1.0f) - 1.0f) * 0.5f);
    while ((bi + 1) * (bi + 2) / 2 <= j) ++bi;
    while (bi * (bi + 1) / 2 > j) --bi;
    const int bj = j - bi * (bi + 1) / 2;         // bj <= bi
    const int bz = blockIdx.z;

    tile128<1>(lds,
               qp + (size_t)bz * 2048 * 1024,
               kp + (size_t)bz * 2048 * 1024,
               P + (size_t)bz * 2048 * 2048, nullptr, nullptr,
               1024, 1024, 2048,
               bi * 128, bj * 128, 16, 0.03125f, threadIdx.x);
}

// PV: pair (pid, 15-pid) per block; grid x = pid*4+bz so the 8 bj-blocks of a
// (pid,bz) group share blockIdx%8 -> same XCD -> P strip stays in its L2.
__launch_bounds__(512, 4)
__global__ void pv128(const bf16* __restrict__ P, const bf16* __restrict__ V,
                      const bf16* __restrict__ R, float* __restrict__ C)
{
    extern __shared__ char lds[];
    const int g = blockIdx.x;                 // 0..31
    const int pid = g >> 2, bz = g & 3;
    const int bj = blockIdx.y;                // 0..7
    const bf16* Pb = P + (size_t)bz * 2048 * 2048;
    const bf16* Vb = V + (size_t)bz * 1024 * 2048;
    const bf16* Rb = R + (size_t)bz * 2048 * 1024;
    float* Cb = C + (size_t)bz * 2048 * 1024;
    const int bcol = bj * 128;
    const int tid = threadIdx.x;

    tile128<2>(lds, Pb, Vb, nullptr, Cb, Rb, 2048, 2048, 1024,
               pid * 128, bcol, 2 * (pid + 1), 1.0f, tid);
    asm volatile("s_waitcnt vmcnt(0) lgkmcnt(0)" ::: "memory");
    __builtin_amdgcn_s_barrier();
    const int bi2 = 15 - pid;
    tile128<2>(lds, Pb, Vb, nullptr, Cb, Rb, 2048, 2048, 1024,
               bi2 * 128, bcol, 2 * (bi2 + 1), 1.0f, tid);
}

// fp32 -> bf16 convert of q,k,v into stacked [3*8192][1024], 16B stores
__global__ void convert_qkv(const float* __restrict__ q, const float* __restrict__ k,
                            const float* __restrict__ v, bf16* __restrict__ Xb)
{
    const int N8 = 8192 * 1024 / 8;
    const int total = 3 * N8;
    for (int i = blockIdx.x * 256 + threadIdx.x; i < total; i += gridDim.x * 256) {
        const int t = i / N8, j = i - t * N8;
        const float4* s = (t == 0) ? (const float4*)q
                        : (t == 1) ? (const float4*)k : (const float4*)v;
        float4 a = s[2 * j], bq = s[2 * j + 1];
        float vals[8] = {a.x, a.y, a.z, a.w, bq.x, bq.y, bq.z, bq.w};
        union { short h[8]; bf16x8 v8; } o;
        #pragma unroll
        for (int e = 0; e < 8; ++e) {
            bf16 hh = __float2bfloat16(vals[e]);
            o.h[e] = *(short*)&hh;
        }
        ((bf16x8*)Xb)[i] = o.v8;
    }
}

// Wt[n][k] = bf16(wi[k][n]),  1024x1024
__global__ void transpose_wi(const float* __restrict__ wi, bf16* __restrict__ Wt)
{
    __shared__ float t[32][33];
    const int n0 = blockIdx.x * 32, k0 = blockIdx.y * 32;
    const int lx = threadIdx.x & 31, ly = threadIdx.x >> 5;
    for (int i = ly; i < 32; i += 8)
        t[i][lx] = wi[(size_t)(k0 + i) * 1024 + n0 + lx];
    __syncthreads();
    for (int i = ly; i < 32; i += 8)
        Wt[(size_t)(n0 + i) * 1024 + k0 + lx] = __float2bfloat16(t[lx][i]);
}

// wave-per-row causal softmax, zero-fill to 128-aligned boundary
__launch_bounds__(256)
__global__ void softmax_rows(bf16* __restrict__ P)
{
    const int wid = threadIdx.x >> 6, lane = threadIdx.x & 63;
    const int r = blockIdx.x * 4 + wid, b = blockIdx.y;
    bf16* row = P + ((size_t)b * 2048 + r) * 2048;
    const int nv  = r + 1;
    const int rup = (r & ~127) + 128;

    float vals[4][8];
    float m = -1e30f;
    #pragma unroll
    for (int c = 0; c < 4; ++c) {
        const int k0 = c * 512 + lane * 8;
        if (k0 < rup) {
            bf16x8 x = *(const bf16x8*)(row + k0);
            #pragma unroll
            for (int j = 0; j < 8; ++j) {
                float f = (k0 + j < nv) ? bf2f(x[j]) : -1e30f;
                vals[c][j] = f;
                m = fmaxf(m, f);
            }
        } else {
            #pragma unroll
            for (int j = 0; j < 8; ++j) vals[c][j] = -1e30f;
        }
    }
    #pragma unroll
    for (int o = 32; o; o >>= 1) m = fmaxf(m, __shfl_xor(m, o));

    float sum = 0.f;
    #pragma unroll
    for (int c = 0; c < 4; ++c)
        #pragma unroll
        for (int j = 0; j < 8; ++j) {
            float e = __expf(vals[c][j] - m);
            vals[c][j] = e;
            sum += e;
        }
    #pragma unroll
    for (int o = 32; o; o >>= 1) sum += __shfl_xor(sum, o);
    const float inv = 1.0f / sum;

    #pragma unroll
    for (int c = 0; c < 4; ++c) {
        const int k0 = c * 512 + lane * 8;
        if (k0 < rup) {
            union { short h[8]; bf16x8 v8; } o;
            #pragma unroll
            for (int j = 0; j < 8; ++j) {
                bf16 hh = __float2bfloat16(vals[c][j] * inv);
                o.h[j] = *(short*)&hh;
            }
            *(bf16x8*)(row + k0) = o.v8;
        }
    }
}

extern "C" void kernel_launch(void* const* d_in, const int* in_sizes, int n_in,
                              void* d_out, int out_size, void* d_ws, size_t ws_size,
                              hipStream_t stream)
{
    const float* v  = (const float*)d_in[0];
    const float* k  = (const float*)d_in[1];
    const float* q  = (const float*)d_in[2];
    const float* wi = (const float*)d_in[3];
    float* out = (float*)d_out;

    char* ws = (char*)d_ws;
    const size_t WT_OFF   = 0;                       // 2 MB
    const size_t PROJ_OFF = WT_OFF + (2u << 20);     // 48 MB
    const size_t VPT_OFF  = PROJ_OFF + (size_t)24576 * 1024 * 2;   // 16 MB
    const size_t XB_OFF   = VPT_OFF + (size_t)4 * 1024 * 2048 * 2; // 48 MB

    bf16* Wt   = (bf16*)(ws + WT_OFF);
    bf16* proj = (bf16*)(ws + PROJ_OFF);   // [q(8192)|k(8192)|(v unused)] x 1024
    bf16* vpT  = (bf16*)(ws + VPT_OFF);    // [4][1024][2048] (written by proj)
    bf16* Xb   = (bf16*)(ws + XB_OFF);     // [24576][1024] bf16 X
    bf16* P    = Xb;                       // P [4][2048][2048] aliases Xb (dead)

    bf16* qp_b = proj;
    bf16* kp_b = proj + (size_t)8192 * 1024;

    (void)hipFuncSetAttribute((const void*)proj_bn128,
            hipFuncAttributeMaxDynamicSharedMemorySize, 98304);
    (void)hipFuncSetAttribute((const void*)scores128,
            hipFuncAttributeMaxDynamicSharedMemorySize, 81920);
    (void)hipFuncSetAttribute((const void*)pv128,
            hipFuncAttributeMaxDynamicSharedMemorySize, 81920);

    transpose_wi<<<dim3(32, 32), 256, 0, stream>>>(wi, Wt);
    convert_qkv<<<2048, 256, 0, stream>>>(q, k, v, Xb);

    // projection: 768 blocks = 3 exact rounds; v-part written transposed
    proj_bn128<<<dim3(8, 96), 512, 98304, stream>>>(Xb, Wt, proj, vpT);

    // scores: triangular 136 tiles/batch, 128x128 split-K, 2 blocks/CU
    scores128<<<dim3(136, 1, 4), 512, 81920, stream>>>(qp_b, kp_b, P);

    softmax_rows<<<dim3(512, 4), 256, 0, stream>>>(P);

    // PV: causal-balanced pairs, XCD-grouped by (pid,bz)
    pv128<<<dim3(32, 8), 512, 81920, stream>>>(P, vpT, qp_b, out);
}

// Round 9
// 180.624 us; speedup vs baseline: 1.0334x; 1.0334x over previous
//
#include <hip/hip_runtime.h>
#include <hip/hip_bf16.h>

typedef __hip_bfloat16 bf16;
typedef short bf16x8 __attribute__((ext_vector_type(8)));
typedef float f32x4 __attribute__((ext_vector_type(4)));

#define HT 16384   // bf16 half-tile bytes: 128 rows x 64 cols

__device__ __forceinline__ void gload16(const void* g, void* l) {
    __builtin_amdgcn_global_load_lds(
        (const __attribute__((address_space(1))) void*)g,
        (__attribute__((address_space(3))) void*)l, 16, 0, 0);
}

// Stage one 128x64 bf16 half-tile into LDS slot slotIdx (16 KiB units).
// Linear LDS dest; source pre-swizzled with involution chunk ^= row&7.
__device__ __forceinline__ void stage_half(char* lds, const bf16* src, int ld,
                                           int rowbase, int k0, int slotIdx,
                                           int tid)
{
    char* dst = lds + (size_t)slotIdx * HT + tid * 16;
    const int sub = tid >> 3;
    const int cb  = ((tid & 7) ^ (sub & 7)) << 4;
    #pragma unroll
    for (int p = 0; p < 2; ++p) {
        const int row = p * 64 + sub;
        const char* g = (const char*)(src + (size_t)(rowbase + row) * ld + k0) + cb;
        gload16(g, dst + p * 8192);
    }
}

// read one MFMA A/B fragment (8 bf16 = 16B) with the read-side swizzle
__device__ __forceinline__ bf16x8 ldsfrag(const char* lds, int slotIdx,
                                          int row, int ks, int cb0)
{
    return *(const bf16x8*)(lds + (size_t)slotIdx * HT
                            + row * 128 + (cb0 ^ (ks << 6)));
}

__device__ __forceinline__ float bf2f(short s) {
    union { float f; unsigned u; } c;
    c.u = ((unsigned)(unsigned short)s) << 16;
    return c.f;
}

// ====== projection, DEEP pipeline: BM=256 BN=128, 8 waves 4Mx2N ======
// LDS 144 KiB: A bufs {0,1}{2,3}{4,5} (tile=2 half-slots, x3), B bufs 6,7,8.
// Stage A(t+2) at ph0/ph1 (7-phase cover > HBM latency), B(t+3) at ph2,
// counted vmcnt(6) at ph3 -- never drains the pipeline.
__launch_bounds__(512, 2)
__global__ void proj_deep(const bf16* __restrict__ A, const bf16* __restrict__ B,
                          bf16* __restrict__ C)
{
    extern __shared__ char lds[];
    const int orig = blockIdx.y * 8 + blockIdx.x;      // 768 blocks
    const int wk2 = (orig & 7) * 96 + (orig >> 3);     // bijective, 96/XCD
    const int bi = wk2 >> 3, bj = wk2 & 7;             // bi 0..95, bj 0..7
    const int brow = bi * 256, bcol = bj * 128;

    const int tid  = threadIdx.x;
    const int lane = tid & 63;
    const int w    = tid >> 6;
    const int wm   = w >> 1, wn = w & 1;
    const int fr   = lane & 15, fq = lane >> 4;
    const int cb0  = ((fr & 7) ^ fq) << 4;
    const int hA    = wm >> 1;           // which A half-slot within buf
    const int rA    = (wm & 1) * 64;
    const int rB    = wn * 64;
    const int NT    = 16;                // K=1024/64

    f32x4 acc[4][4] = {};
    bf16x8 af[4][2], bv[4][2];

    // prologue: A(0),B(0) then A(1),B(1),B(2); drain first 6 loads only
    stage_half(lds, A, 1024, brow,       0, 0, tid);
    stage_half(lds, A, 1024, brow + 128, 0, 1, tid);
    stage_half(lds, B, 1024, bcol,       0, 6, tid);
    stage_half(lds, A, 1024, brow,      64, 2, tid);
    stage_half(lds, A, 1024, brow + 128,64, 3, tid);
    stage_half(lds, B, 1024, bcol,     64, 7, tid);
    stage_half(lds, B, 1024, bcol,    128, 8, tid);
    asm volatile("s_waitcnt vmcnt(8)" ::: "memory");
    __builtin_amdgcn_s_barrier();

#define QUAD2(m0, n0)                                                         \
    _Pragma("unroll") for (int dm = 0; dm < 2; ++dm)                          \
    _Pragma("unroll") for (int dn = 0; dn < 2; ++dn)                          \
    _Pragma("unroll") for (int ks = 0; ks < 2; ++ks)                          \
        acc[(m0)+dm][(n0)+dn] = __builtin_amdgcn_mfma_f32_16x16x32_bf16(      \
            af[(m0)+dm][ks], bv[(n0)+dn][ks], acc[(m0)+dm][(n0)+dn], 0, 0, 0);

    for (int t = 0; t < NT; ++t) {
        const int ab  = t % 3;                       // A buf being read
        const int bb  = 6 + ab;                      // B buf being read
        const int ab2 = ((t + 2) % 3) * 2;           // A dest buf (half-slot base)
        const int kA  = min(t + 2, NT - 1) << 6;
        const int kB  = min(t + 3, NT - 1) << 6;
        const int slotA = ab * 2 + hA;

        // ph0: read af01 + bv01; stage A0(t+2)
        #pragma unroll
        for (int m = 0; m < 2; ++m)
            #pragma unroll
            for (int ks = 0; ks < 2; ++ks)
                af[m][ks] = ldsfrag(lds, slotA, rA + m * 16 + fr, ks, cb0);
        #pragma unroll
        for (int n = 0; n < 2; ++n)
            #pragma unroll
            for (int ks = 0; ks < 2; ++ks)
                bv[n][ks] = ldsfrag(lds, bb, rB + n * 16 + fr, ks, cb0);
        stage_half(lds, A, 1024, brow, kA, ab2, tid);
        __builtin_amdgcn_s_barrier();
        __builtin_amdgcn_s_setprio(1);
        QUAD2(0, 0)
        __builtin_amdgcn_s_setprio(0);
        __builtin_amdgcn_s_barrier();

        // ph1: read bv23; stage A1(t+2)
        #pragma unroll
        for (int n = 2; n < 4; ++n)
            #pragma unroll
            for (int ks = 0; ks < 2; ++ks)
                bv[n][ks] = ldsfrag(lds, bb, rB + n * 16 + fr, ks, cb0);
        stage_half(lds, A, 1024, brow + 128, kA, ab2 + 1, tid);
        __builtin_amdgcn_s_barrier();
        __builtin_amdgcn_s_setprio(1);
        QUAD2(0, 2)
        __builtin_amdgcn_s_setprio(0);
        __builtin_amdgcn_s_barrier();

        // ph2: read af23; stage B(t+3) (B-buf t%3: reads drained by ph1)
        #pragma unroll
        for (int m = 2; m < 4; ++m)
            #pragma unroll
            for (int ks = 0; ks < 2; ++ks)
                af[m][ks] = ldsfrag(lds, slotA, rA + m * 16 + fr, ks, cb0);
        stage_half(lds, B, 1024, bcol, kB, bb, tid);
        __builtin_amdgcn_s_barrier();
        __builtin_amdgcn_s_setprio(1);
        QUAD2(2, 2)
        __builtin_amdgcn_s_setprio(0);
        __builtin_amdgcn_s_barrier();

        // ph3: last quadrant; vmcnt(6) = leave {A(t+2), B(t+3)} in flight
        __builtin_amdgcn_s_setprio(1);
        QUAD2(2, 0)
        __builtin_amdgcn_s_setprio(0);
        asm volatile("s_waitcnt vmcnt(6)" ::: "memory");
        __builtin_amdgcn_s_barrier();
    }
#undef QUAD2

    #pragma unroll
    for (int mf = 0; mf < 4; ++mf) {
        const int r0 = brow + wm * 64 + mf * 16 + fq * 4;
        #pragma unroll
        for (int nf = 0; nf < 4; ++nf) {
            const int c = bcol + wn * 64 + nf * 16 + fr;
            #pragma unroll
            for (int j = 0; j < 4; ++j)
                C[(size_t)(r0 + j) * 1024 + c] = __float2bfloat16(acc[mf][nf][j]);
        }
    }
}

// ====== 128x128 tile engine (R7, 2-phase, A 3-rotation + B dbuf, 80 KiB) ====
// 8 waves 2Mx4N (wave 64x32). MODE 1: Cb = scale*(A@B^T) bf16.
// MODE 2: Cf = A@B^T + Res f32.
template<int MODE>
__device__ __forceinline__ void tile128(char* lds, const bf16* A, const bf16* B,
                                        bf16* Cb, float* Cf, const bf16* Res,
                                        int lda, int ldb, int ldcb,
                                        int brow, int bcol, int NT, float scale,
                                        int tid, int wm, int wn, int fr, int fq,
                                        int cb0)
{
    f32x4 acc[4][2] = {};
    bf16x8 af[4][2], bv[2][2];

    stage_half(lds, A, lda, brow, 0,  0, tid);
    stage_half(lds, B, ldb, bcol, 0,  3, tid);
    stage_half(lds, A, lda, brow, 64, 1, tid);
    stage_half(lds, B, ldb, bcol, 64, 4, tid);
    asm volatile("s_waitcnt vmcnt(4)" ::: "memory");
    __builtin_amdgcn_s_barrier();

    for (int t = 0; t < NT; ++t) {
        const int aslot = t % 3, bslot = 3 + (t & 1);
        const int k2 = min(t + 2, NT - 1) << 6;

        // ph0: read af01 + bv01; stage A(t+2) into free A slot
        #pragma unroll
        for (int m = 0; m < 2; ++m)
            #pragma unroll
            for (int ks = 0; ks < 2; ++ks)
                af[m][ks] = ldsfrag(lds, aslot, wm * 64 + m * 16 + fr, ks, cb0);
        #pragma unroll
        for (int n = 0; n < 2; ++n)
            #pragma unroll
            for (int ks = 0; ks < 2; ++ks)
                bv[n][ks] = ldsfrag(lds, bslot, wn * 32 + n * 16 + fr, ks, cb0);
        stage_half(lds, A, lda, brow, k2, (t + 2) % 3, tid);
        __builtin_amdgcn_s_barrier();
        __builtin_amdgcn_s_setprio(1);
        #pragma unroll
        for (int m = 0; m < 2; ++m)
            #pragma unroll
            for (int n = 0; n < 2; ++n)
                #pragma unroll
                for (int ks = 0; ks < 2; ++ks)
                    acc[m][n] = __builtin_amdgcn_mfma_f32_16x16x32_bf16(
                        af[m][ks], bv[n][ks], acc[m][n], 0, 0, 0);
        __builtin_amdgcn_s_setprio(0);
        __builtin_amdgcn_s_barrier();

        // ph1: read af23; stage B(t+2) (reads of bslot completed in ph0)
        #pragma unroll
        for (int m = 2; m < 4; ++m)
            #pragma unroll
            for (int ks = 0; ks < 2; ++ks)
                af[m][ks] = ldsfrag(lds, aslot, wm * 64 + m * 16 + fr, ks, cb0);
        stage_half(lds, B, ldb, bcol, k2, bslot, tid);
        __builtin_amdgcn_s_barrier();
        __builtin_amdgcn_s_setprio(1);
        #pragma unroll
        for (int m = 2; m < 4; ++m)
            #pragma unroll
            for (int n = 0; n < 2; ++n)
                #pragma unroll
                for (int ks = 0; ks < 2; ++ks)
                    acc[m][n] = __builtin_amdgcn_mfma_f32_16x16x32_bf16(
                        af[m][ks], bv[n][ks], acc[m][n], 0, 0, 0);
        __builtin_amdgcn_s_setprio(0);
        asm volatile("s_waitcnt vmcnt(4)" ::: "memory");   // tile t+1 resident
        __builtin_amdgcn_s_barrier();
    }

    #pragma unroll
    for (int mf = 0; mf < 4; ++mf) {
        const int r0 = brow + wm * 64 + mf * 16 + fq * 4;
        #pragma unroll
        for (int nf = 0; nf < 2; ++nf) {
            const int c = bcol + wn * 32 + nf * 16 + fr;
            #pragma unroll
            for (int j = 0; j < 4; ++j) {
                if (MODE == 1)
                    Cb[(size_t)(r0 + j) * ldcb + c] =
                        __float2bfloat16(acc[mf][nf][j] * scale);
                else
                    Cf[(size_t)(r0 + j) * ldcb + c] = acc[mf][nf][j] +
                        __bfloat162float(Res[(size_t)(r0 + j) * ldcb + c]);
            }
        }
    }
}

// scores: triangular grid, per batch 136 tiles of 128x128; P = qp@kp^T * 1/32
__launch_bounds__(512, 4)
__global__ void scores128(const bf16* __restrict__ qp, const bf16* __restrict__ kp,
                          bf16* __restrict__ P)
{
    extern __shared__ char lds[];
    const int j = blockIdx.x;                     // 0..135
    int bi = (int)((__fsqrt_rn(8.0f * j + 1.0f) - 1.0f) * 0.5f);
    while ((bi + 1) * (bi + 2) / 2 <= j) ++bi;
    while (bi * (bi + 1) / 2 > j) --bi;
    const int bj = j - bi * (bi + 1) / 2;         // bj <= bi
    const int bz = blockIdx.z;

    const int tid  = threadIdx.x;
    const int lane = tid & 63;
    const int w    = tid >> 6;
    const int wm   = w >> 2, wn = w & 3;          // 2M x 4N
    const int fr   = lane & 15, fq = lane >> 4;
    const int cb0  = ((fr & 7) ^ fq) << 4;

    tile128<1>(lds,
               qp + (size_t)bz * 2048 * 1024,
               kp + (size_t)bz * 2048 * 1024,
               P + (size_t)bz * 2048 * 2048, nullptr, nullptr,
               1024, 1024, 2048,
               bi * 128, bj * 128, 16, 0.03125f,
               tid, wm, wn, fr, fq, cb0);
}

// PV: causal-balanced pair (bi, 15-bi) per block; O = P@vpT^T + qp residual
__launch_bounds__(512, 4)
__global__ void pv128(const bf16* __restrict__ P, const bf16* __restrict__ V,
                      const bf16* __restrict__ R, float* __restrict__ C)
{
    extern __shared__ char lds[];
    const int pid = blockIdx.x, bj = blockIdx.y, bz = blockIdx.z;
    const bf16* Pb = P + (size_t)bz * 2048 * 2048;
    const bf16* Vb = V + (size_t)bz * 1024 * 2048;
    const bf16* Rb = R + (size_t)bz * 2048 * 1024;
    float* Cb = C + (size_t)bz * 2048 * 1024;

    const int tid  = threadIdx.x;
    const int lane = tid & 63;
    const int w    = tid >> 6;
    const int wm   = w >> 2, wn = w & 3;          // 2M x 4N
    const int fr   = lane & 15, fq = lane >> 4;
    const int cb0  = ((fr & 7) ^ fq) << 4;
    const int bcol = bj * 128;

    tile128<2>(lds, Pb, Vb, nullptr, Cb, Rb, 2048, 2048, 1024,
               pid * 128, bcol, 2 * (pid + 1), 1.0f,
               tid, wm, wn, fr, fq, cb0);
    asm volatile("s_waitcnt vmcnt(0) lgkmcnt(0)" ::: "memory");
    __builtin_amdgcn_s_barrier();
    const int bi2 = 15 - pid;
    tile128<2>(lds, Pb, Vb, nullptr, Cb, Rb, 2048, 2048, 1024,
               bi2 * 128, bcol, 2 * (bi2 + 1), 1.0f,
               tid, wm, wn, fr, fq, cb0);
}

// merged: blocks 0..1023 transpose wi; blocks 1024.. convert q,k,v -> bf16
__global__ void convert_and_wi(const float* __restrict__ q,
                               const float* __restrict__ k,
                               const float* __restrict__ v,
                               const float* __restrict__ wi,
                               bf16* __restrict__ Xb, bf16* __restrict__ Wt)
{
    __shared__ float t[32][33];
    if (blockIdx.x < 1024) {
        const int n0 = (blockIdx.x & 31) * 32, k0 = (blockIdx.x >> 5) * 32;
        const int lx = threadIdx.x & 31, ly = threadIdx.x >> 5;
        for (int i = ly; i < 32; i += 8)
            t[i][lx] = wi[(size_t)(k0 + i) * 1024 + n0 + lx];
        __syncthreads();
        for (int i = ly; i < 32; i += 8)
            Wt[(size_t)(n0 + i) * 1024 + k0 + lx] = __float2bfloat16(t[lx][i]);
        return;
    }
    const int N8 = 8192 * 1024 / 8;
    const int total = 3 * N8;
    const int nconv = gridDim.x - 1024;
    for (int i = (blockIdx.x - 1024) * 256 + threadIdx.x; i < total;
         i += nconv * 256) {
        const int ti = i / N8, j = i - ti * N8;
        const float4* s = (ti == 0) ? (const float4*)q
                        : (ti == 1) ? (const float4*)k : (const float4*)v;
        float4 a = s[2 * j], bq = s[2 * j + 1];
        float vals[8] = {a.x, a.y, a.z, a.w, bq.x, bq.y, bq.z, bq.w};
        union { short h[8]; bf16x8 v8; } o;
        #pragma unroll
        for (int e = 0; e < 8; ++e) {
            bf16 hh = __float2bfloat16(vals[e]);
            o.h[e] = *(short*)&hh;
        }
        ((bf16x8*)Xb)[i] = o.v8;
    }
}

// vpT[b][d][s] = vp[b][s][d]
__global__ void transpose_vp(const bf16* __restrict__ vp, bf16* __restrict__ vpT)
{
    __shared__ bf16 t[32][33];
    const int b = blockIdx.z;
    const int d0 = blockIdx.x * 32, s0 = blockIdx.y * 32;
    const bf16* src = vp + (size_t)b * 2048 * 1024;
    bf16* dst = vpT + (size_t)b * 1024 * 2048;
    const int lx = threadIdx.x & 31, ly = threadIdx.x >> 5;
    for (int i = ly; i < 32; i += 8)
        t[i][lx] = src[(size_t)(s0 + i) * 1024 + d0 + lx];
    __syncthreads();
    for (int i = ly; i < 32; i += 8)
        dst[(size_t)(d0 + i) * 2048 + s0 + lx] = t[lx][i];
}

// wave-per-row causal softmax, zero-fill to 128-aligned boundary
__launch_bounds__(256)
__global__ void softmax_rows(bf16* __restrict__ P)
{
    const int wid = threadIdx.x >> 6, lane = threadIdx.x & 63;
    const int r = blockIdx.x * 4 + wid, b = blockIdx.y;
    bf16* row = P + ((size_t)b * 2048 + r) * 2048;
    const int nv  = r + 1;
    const int rup = (r & ~127) + 128;

    float vals[4][8];
    float m = -1e30f;
    #pragma unroll
    for (int c = 0; c < 4; ++c) {
        const int k0 = c * 512 + lane * 8;
        if (k0 < rup) {
            bf16x8 x = *(const bf16x8*)(row + k0);
            #pragma unroll
            for (int j = 0; j < 8; ++j) {
                float f = (k0 + j < nv) ? bf2f(x[j]) : -1e30f;
                vals[c][j] = f;
                m = fmaxf(m, f);
            }
        } else {
            #pragma unroll
            for (int j = 0; j < 8; ++j) vals[c][j] = -1e30f;
        }
    }
    #pragma unroll
    for (int o = 32; o; o >>= 1) m = fmaxf(m, __shfl_xor(m, o));

    float sum = 0.f;
    #pragma unroll
    for (int c = 0; c < 4; ++c)
        #pragma unroll
        for (int j = 0; j < 8; ++j) {
            float e = __expf(vals[c][j] - m);
            vals[c][j] = e;
            sum += e;
        }
    #pragma unroll
    for (int o = 32; o; o >>= 1) sum += __shfl_xor(sum, o);
    const float inv = 1.0f / sum;

    #pragma unroll
    for (int c = 0; c < 4; ++c) {
        const int k0 = c * 512 + lane * 8;
        if (k0 < rup) {
            union { short h[8]; bf16x8 v8; } o;
            #pragma unroll
            for (int j = 0; j < 8; ++j) {
                bf16 hh = __float2bfloat16(vals[c][j] * inv);
                o.h[j] = *(short*)&hh;
            }
            *(bf16x8*)(row + k0) = o.v8;
        }
    }
}

extern "C" void kernel_launch(void* const* d_in, const int* in_sizes, int n_in,
                              void* d_out, int out_size, void* d_ws, size_t ws_size,
                              hipStream_t stream)
{
    const float* v  = (const float*)d_in[0];
    const float* k  = (const float*)d_in[1];
    const float* q  = (const float*)d_in[2];
    const float* wi = (const float*)d_in[3];
    float* out = (float*)d_out;

    char* ws = (char*)d_ws;
    const size_t WT_OFF   = 0;                       // 2 MB
    const size_t PROJ_OFF = WT_OFF + (2u << 20);     // 48 MB
    const size_t VPT_OFF  = PROJ_OFF + (size_t)24576 * 1024 * 2;   // 16 MB
    const size_t XB_OFF   = VPT_OFF + (size_t)4 * 1024 * 2048 * 2; // 48 MB

    bf16* Wt   = (bf16*)(ws + WT_OFF);
    bf16* proj = (bf16*)(ws + PROJ_OFF);   // [q(8192)|k(8192)|v(8192)] x 1024
    bf16* vpT  = (bf16*)(ws + VPT_OFF);    // [4][1024][2048]
    bf16* Xb   = (bf16*)(ws + XB_OFF);     // [24576][1024] bf16 X
    bf16* P    = Xb;                       // P [4][2048][2048] aliases Xb (dead)

    bf16* qp_b = proj;
    bf16* kp_b = proj + (size_t)8192 * 1024;
    bf16* vp_b = proj + (size_t)16384 * 1024;

    (void)hipFuncSetAttribute((const void*)proj_deep,
            hipFuncAttributeMaxDynamicSharedMemorySize, 147456);
    (void)hipFuncSetAttribute((const void*)scores128,
            hipFuncAttributeMaxDynamicSharedMemorySize, 81920);
    (void)hipFuncSetAttribute((const void*)pv128,
            hipFuncAttributeMaxDynamicSharedMemorySize, 81920);

    // merged wi-transpose + qkv convert
    convert_and_wi<<<3072, 256, 0, stream>>>(q, k, v, wi, Xb, Wt);

    // projection: 768 blocks = 3 exact rounds; deep 3-buffer pipeline
    proj_deep<<<dim3(8, 96), 512, 147456, stream>>>(Xb, Wt, proj);

    transpose_vp<<<dim3(32, 64, 4), 256, 0, stream>>>(vp_b, vpT);

    // scores: triangular 136 tiles/batch, 128x128, 2 blocks/CU
    scores128<<<dim3(136, 1, 4), 512, 81920, stream>>>(qp_b, kp_b, P);

    softmax_rows<<<dim3(512, 4), 256, 0, stream>>>(P);

    // PV: causal-balanced pairs (bi, 15-bi), BM=128, 2 blocks/CU
    pv128<<<dim3(8, 8, 4), 512, 81920, stream>>>(P, vpT, qp_b, out);
}

// Round 10
// 179.077 us; speedup vs baseline: 1.0423x; 1.0086x over previous
//
#include <hip/hip_runtime.h>
#include <hip/hip_bf16.h>

typedef __hip_bfloat16 bf16;
typedef short bf16x8 __attribute__((ext_vector_type(8)));
typedef float f32x4 __attribute__((ext_vector_type(4)));

#define HT 16384   // bf16 half-tile bytes: 128 rows x 64 cols

__device__ __forceinline__ void gload16(const void* g, void* l) {
    __builtin_amdgcn_global_load_lds(
        (const __attribute__((address_space(1))) void*)g,
        (__attribute__((address_space(3))) void*)l, 16, 0, 0);
}

// 512-thread staging of one 128x64 half-tile (2 gload16/thread)
__device__ __forceinline__ void stage_half(char* lds, const bf16* src, int ld,
                                           int rowbase, int k0, int slotIdx,
                                           int tid)
{
    char* dst = lds + (size_t)slotIdx * HT + tid * 16;
    const int sub = tid >> 3;
    const int cb  = ((tid & 7) ^ (sub & 7)) << 4;
    #pragma unroll
    for (int p = 0; p < 2; ++p) {
        const int row = p * 64 + sub;
        const char* g = (const char*)(src + (size_t)(rowbase + row) * ld + k0) + cb;
        gload16(g, dst + p * 8192);
    }
}

// 256-thread staging of one 128x64 half-tile (4 gload16/thread)
__device__ __forceinline__ void stage_q(char* lds, const bf16* src, int ld,
                                        int rowbase, int k0, int slotIdx,
                                        int tid)
{
    char* dst = lds + (size_t)slotIdx * HT + tid * 16;
    #pragma unroll
    for (int p = 0; p < 4; ++p) {
        const int s = p * 256 + tid;
        const int row = s >> 3;
        const int cb = ((s & 7) ^ (row & 7)) << 4;
        const char* g = (const char*)(src + (size_t)(rowbase + row) * ld + k0) + cb;
        gload16(g, dst + p * 4096);
    }
}

// read one MFMA A/B fragment (8 bf16 = 16B) with the read-side swizzle
__device__ __forceinline__ bf16x8 ldsfrag(const char* lds, int slotIdx,
                                          int row, int ks, int cb0)
{
    return *(const bf16x8*)(lds + (size_t)slotIdx * HT
                            + row * 128 + (cb0 ^ (ks << 6)));
}

__device__ __forceinline__ float bf2f(short s) {
    union { float f; unsigned u; } c;
    c.u = ((unsigned)(unsigned short)s) << 16;
    return c.f;
}

// ====== projection, 2-phase x 16-MFMA: BM=256 BN=128, 8 waves 4Mx2N ======
// LDS 128 KiB: A slots 0..5 (3-rotation x 2 halves), B slots 6,7 (dbuf).
// ph0: read all frags + stage A(t+2); ph1: stage B(t+2); vmcnt(6) counted.
__launch_bounds__(512, 2)
__global__ void proj_2ph(const bf16* __restrict__ A, const bf16* __restrict__ B,
                         bf16* __restrict__ C)
{
    extern __shared__ char lds[];
    const int orig = blockIdx.y * 8 + blockIdx.x;      // 768 blocks
    const int wk2 = (orig & 7) * 96 + (orig >> 3);     // bijective, 96/XCD
    const int bi = wk2 >> 3, bj = wk2 & 7;             // bi 0..95, bj 0..7
    const int brow = bi * 256, bcol = bj * 128;

    const int tid  = threadIdx.x;
    const int lane = tid & 63;
    const int w    = tid >> 6;
    const int wm   = w >> 1, wn = w & 1;               // 4M x 2N, wave 64x64
    const int fr   = lane & 15, fq = lane >> 4;
    const int cb0  = ((fr & 7) ^ fq) << 4;
    const int hA   = wm >> 1;            // which 128-half of A this wave reads
    const int rA   = (wm & 1) * 64;
    const int rB   = wn * 64;
    const int NT   = 16;                 // K=1024/64

    f32x4 acc[4][4] = {};
    bf16x8 af[4][2], bv[4][2];

    // prologue: A(0)->slots 0,1; B(0)->6; A(1)->2,3; B(1)->7
    stage_half(lds, A, 1024, brow,       0, 0, tid);
    stage_half(lds, A, 1024, brow + 128, 0, 1, tid);
    stage_half(lds, B, 1024, bcol,       0, 6, tid);
    stage_half(lds, A, 1024, brow,      64, 2, tid);
    stage_half(lds, A, 1024, brow + 128,64, 3, tid);
    stage_half(lds, B, 1024, bcol,     64, 7, tid);
    asm volatile("s_waitcnt vmcnt(6)" ::: "memory");
    __builtin_amdgcn_s_barrier();

#define MF8(n0)                                                               \
    _Pragma("unroll") for (int m = 0; m < 4; ++m)                             \
    _Pragma("unroll") for (int dn = 0; dn < 2; ++dn)                          \
    _Pragma("unroll") for (int ks = 0; ks < 2; ++ks)                          \
        acc[m][(n0)+dn] = __builtin_amdgcn_mfma_f32_16x16x32_bf16(            \
            af[m][ks], bv[(n0)+dn][ks], acc[m][(n0)+dn], 0, 0, 0);

    for (int t = 0; t < NT; ++t) {
        const int aslot = (t % 3) * 2 + hA;
        const int bslot = 6 + (t & 1);
        const int a2    = ((t + 2) % 3) * 2;
        const int k2    = min(t + 2, NT - 1) << 6;

        // ph0: read all 16 frags; stage A(t+2)
        #pragma unroll
        for (int m = 0; m < 4; ++m)
            #pragma unroll
            for (int ks = 0; ks < 2; ++ks)
                af[m][ks] = ldsfrag(lds, aslot, rA + m * 16 + fr, ks, cb0);
        #pragma unroll
        for (int n = 0; n < 4; ++n)
            #pragma unroll
            for (int ks = 0; ks < 2; ++ks)
                bv[n][ks] = ldsfrag(lds, bslot, rB + n * 16 + fr, ks, cb0);
        stage_half(lds, A, 1024, brow,       k2, a2,     tid);
        stage_half(lds, A, 1024, brow + 128, k2, a2 + 1, tid);
        __builtin_amdgcn_s_barrier();
        __builtin_amdgcn_s_setprio(1);
        MF8(0)
        __builtin_amdgcn_s_setprio(0);
        __builtin_amdgcn_s_barrier();

        // ph1: stage B(t+2) (bv fully read in ph0; dbuf safe after barrier)
        stage_half(lds, B, 1024, bcol, k2, bslot, tid);
        __builtin_amdgcn_s_barrier();
        __builtin_amdgcn_s_setprio(1);
        MF8(2)
        __builtin_amdgcn_s_setprio(0);
        asm volatile("s_waitcnt vmcnt(6)" ::: "memory");
        __builtin_amdgcn_s_barrier();
    }
#undef MF8

    #pragma unroll
    for (int mf = 0; mf < 4; ++mf) {
        const int r0 = brow + wm * 64 + mf * 16 + fq * 4;
        #pragma unroll
        for (int nf = 0; nf < 4; ++nf) {
            const int c = bcol + wn * 64 + nf * 16 + fr;
            #pragma unroll
            for (int j = 0; j < 4; ++j)
                C[(size_t)(r0 + j) * 1024 + c] = __float2bfloat16(acc[mf][nf][j]);
        }
    }
}

// ====== engine v2: 256 thr, 4 waves 2Mx2N (wave 64x64), block 128x128 ======
// LDS: A slots 0,1,2 (3-rot) + B slots 3,4 (dbuf) = 80 KiB -> 2 blocks/CU.
// 2 phases x 16 MFMA; all frags read in ph0; vmcnt(8) counted.
template<int MODE>
__device__ __forceinline__ void tile128v2(char* lds, const bf16* A, const bf16* B,
                                          bf16* Cb, float* Cf, const bf16* Res,
                                          int lda, int ldb, int ldcb,
                                          int brow, int bcol, int NT, float scale,
                                          int tid)
{
    const int lane = tid & 63;
    const int w    = tid >> 6;            // 0..3
    const int wm   = w >> 1, wn = w & 1;
    const int fr   = lane & 15, fq = lane >> 4;
    const int cb0  = ((fr & 7) ^ fq) << 4;

    f32x4 acc[4][4] = {};
    bf16x8 af[4][2], bv[4][2];

    stage_q(lds, A, lda, brow, 0,  0, tid);
    stage_q(lds, B, ldb, bcol, 0,  3, tid);
    stage_q(lds, A, lda, brow, 64, 1, tid);
    stage_q(lds, B, ldb, bcol, 64, 4, tid);
    asm volatile("s_waitcnt vmcnt(8)" ::: "memory");
    __builtin_amdgcn_s_barrier();

    for (int t = 0; t < NT; ++t) {
        const int aslot = t % 3, bslot = 3 + (t & 1);
        const int k2 = min(t + 2, NT - 1) << 6;

        // ph0: read all 16 frags; stage A(t+2)
        #pragma unroll
        for (int m = 0; m < 4; ++m)
            #pragma unroll
            for (int ks = 0; ks < 2; ++ks)
                af[m][ks] = ldsfrag(lds, aslot, wm * 64 + m * 16 + fr, ks, cb0);
        #pragma unroll
        for (int n = 0; n < 4; ++n)
            #pragma unroll
            for (int ks = 0; ks < 2; ++ks)
                bv[n][ks] = ldsfrag(lds, bslot, wn * 64 + n * 16 + fr, ks, cb0);
        stage_q(lds, A, lda, brow, k2, (t + 2) % 3, tid);
        __builtin_amdgcn_s_barrier();
        __builtin_amdgcn_s_setprio(1);
        #pragma unroll
        for (int m = 0; m < 4; ++m)
            #pragma unroll
            for (int n = 0; n < 2; ++n)
                #pragma unroll
                for (int ks = 0; ks < 2; ++ks)
                    acc[m][n] = __builtin_amdgcn_mfma_f32_16x16x32_bf16(
                        af[m][ks], bv[n][ks], acc[m][n], 0, 0, 0);
        __builtin_amdgcn_s_setprio(0);
        __builtin_amdgcn_s_barrier();

        // ph1: stage B(t+2) (bv fully read in ph0)
        stage_q(lds, B, ldb, bcol, k2, bslot, tid);
        __builtin_amdgcn_s_barrier();
        __builtin_amdgcn_s_setprio(1);
        #pragma unroll
        for (int m = 0; m < 4; ++m)
            #pragma unroll
            for (int n = 2; n < 4; ++n)
                #pragma unroll
                for (int ks = 0; ks < 2; ++ks)
                    acc[m][n] = __builtin_amdgcn_mfma_f32_16x16x32_bf16(
                        af[m][ks], bv[n][ks], acc[m][n], 0, 0, 0);
        __builtin_amdgcn_s_setprio(0);
        asm volatile("s_waitcnt vmcnt(8)" ::: "memory");
        __builtin_amdgcn_s_barrier();
    }

    #pragma unroll
    for (int mf = 0; mf < 4; ++mf) {
        const int r0 = brow + wm * 64 + mf * 16 + fq * 4;
        #pragma unroll
        for (int nf = 0; nf < 4; ++nf) {
            const int c = bcol + wn * 64 + nf * 16 + fr;
            #pragma unroll
            for (int j = 0; j < 4; ++j) {
                if (MODE == 1)
                    Cb[(size_t)(r0 + j) * ldcb + c] =
                        __float2bfloat16(acc[mf][nf][j] * scale);
                else
                    Cf[(size_t)(r0 + j) * ldcb + c] = acc[mf][nf][j] +
                        __bfloat162float(Res[(size_t)(r0 + j) * ldcb + c]);
            }
        }
    }
}

// scores: triangular grid, per batch 136 tiles of 128x128; P = qp@kp^T * 1/32
__launch_bounds__(256, 2)
__global__ void scores128(const bf16* __restrict__ qp, const bf16* __restrict__ kp,
                          bf16* __restrict__ P)
{
    extern __shared__ char lds[];
    const int j = blockIdx.x;                     // 0..135
    int bi = (int)((__fsqrt_rn(8.0f * j + 1.0f) - 1.0f) * 0.5f);
    while ((bi + 1) * (bi + 2) / 2 <= j) ++bi;
    while (bi * (bi + 1) / 2 > j) --bi;
    const int bj = j - bi * (bi + 1) / 2;         // bj <= bi
    const int bz = blockIdx.z;

    tile128v2<1>(lds,
                 qp + (size_t)bz * 2048 * 1024,
                 kp + (size_t)bz * 2048 * 1024,
                 P + (size_t)bz * 2048 * 2048, nullptr, nullptr,
                 1024, 1024, 2048,
                 bi * 128, bj * 128, 16, 0.03125f, threadIdx.x);
}

// PV: 512 single-tile blocks; x and x+256 carry complementary bi so each
// CU's two resident blocks sum to a constant 34 K-steps (balanced).
__launch_bounds__(256, 2)
__global__ void pv128(const bf16* __restrict__ P, const bf16* __restrict__ V,
                      const bf16* __restrict__ R, float* __restrict__ C)
{
    extern __shared__ char lds[];
    const int x  = blockIdx.x;                // 0..511
    const int u  = x & 255;
    const int bs = u & 7;
    const int bj = (u >> 3) & 7;
    const int bz = u >> 6;
    const int bi = (x >> 8) ? (15 - bs) : bs;

    tile128v2<2>(lds,
                 P + (size_t)bz * 2048 * 2048,
                 V + (size_t)bz * 1024 * 2048,
                 nullptr,
                 C + (size_t)bz * 2048 * 1024,
                 R + (size_t)bz * 2048 * 1024,
                 2048, 2048, 1024,
                 bi * 128, bj * 128, 2 * (bi + 1), 1.0f, threadIdx.x);
}

// merged: blocks 0..1023 transpose wi; blocks 1024.. convert q,k,v -> bf16
__global__ void convert_and_wi(const float* __restrict__ q,
                               const float* __restrict__ k,
                               const float* __restrict__ v,
                               const float* __restrict__ wi,
                               bf16* __restrict__ Xb, bf16* __restrict__ Wt)
{
    __shared__ float t[32][33];
    if (blockIdx.x < 1024) {
        const int n0 = (blockIdx.x & 31) * 32, k0 = (blockIdx.x >> 5) * 32;
        const int lx = threadIdx.x & 31, ly = threadIdx.x >> 5;
        for (int i = ly; i < 32; i += 8)
            t[i][lx] = wi[(size_t)(k0 + i) * 1024 + n0 + lx];
        __syncthreads();
        for (int i = ly; i < 32; i += 8)
            Wt[(size_t)(n0 + i) * 1024 + k0 + lx] = __float2bfloat16(t[lx][i]);
        return;
    }
    const int N8 = 8192 * 1024 / 8;
    const int total = 3 * N8;
    const int nconv = gridDim.x - 1024;
    for (int i = (blockIdx.x - 1024) * 256 + threadIdx.x; i < total;
         i += nconv * 256) {
        const int ti = i / N8, j = i - ti * N8;
        const float4* s = (ti == 0) ? (const float4*)q
                        : (ti == 1) ? (const float4*)k : (const float4*)v;
        float4 a = s[2 * j], bq = s[2 * j + 1];
        float vals[8] = {a.x, a.y, a.z, a.w, bq.x, bq.y, bq.z, bq.w};
        union { short h[8]; bf16x8 v8; } o;
        #pragma unroll
        for (int e = 0; e < 8; ++e) {
            bf16 hh = __float2bfloat16(vals[e]);
            o.h[e] = *(short*)&hh;
        }
        ((bf16x8*)Xb)[i] = o.v8;
    }
}

// vpT[b][d][s] = vp[b][s][d]
__global__ void transpose_vp(const bf16* __restrict__ vp, bf16* __restrict__ vpT)
{
    __shared__ bf16 t[32][33];
    const int b = blockIdx.z;
    const int d0 = blockIdx.x * 32, s0 = blockIdx.y * 32;
    const bf16* src = vp + (size_t)b * 2048 * 1024;
    bf16* dst = vpT + (size_t)b * 1024 * 2048;
    const int lx = threadIdx.x & 31, ly = threadIdx.x >> 5;
    for (int i = ly; i < 32; i += 8)
        t[i][lx] = src[(size_t)(s0 + i) * 1024 + d0 + lx];
    __syncthreads();
    for (int i = ly; i < 32; i += 8)
        dst[(size_t)(d0 + i) * 2048 + s0 + lx] = t[lx][i];
}

// wave-per-row causal softmax, zero-fill to 128-aligned boundary
__launch_bounds__(256)
__global__ void softmax_rows(bf16* __restrict__ P)
{
    const int wid = threadIdx.x >> 6, lane = threadIdx.x & 63;
    const int r = blockIdx.x * 4 + wid, b = blockIdx.y;
    bf16* row = P + ((size_t)b * 2048 + r) * 2048;
    const int nv  = r + 1;
    const int rup = (r & ~127) + 128;

    float vals[4][8];
    float m = -1e30f;
    #pragma unroll
    for (int c = 0; c < 4; ++c) {
        const int k0 = c * 512 + lane * 8;
        if (k0 < rup) {
            bf16x8 x = *(const bf16x8*)(row + k0);
            #pragma unroll
            for (int j = 0; j < 8; ++j) {
                float f = (k0 + j < nv) ? bf2f(x[j]) : -1e30f;
                vals[c][j] = f;
                m = fmaxf(m, f);
            }
        } else {
            #pragma unroll
            for (int j = 0; j < 8; ++j) vals[c][j] = -1e30f;
        }
    }
    #pragma unroll
    for (int o = 32; o; o >>= 1) m = fmaxf(m, __shfl_xor(m, o));

    float sum = 0.f;
    #pragma unroll
    for (int c = 0; c < 4; ++c)
        #pragma unroll
        for (int j = 0; j < 8; ++j) {
            float e = __expf(vals[c][j] - m);
            vals[c][j] = e;
            sum += e;
        }
    #pragma unroll
    for (int o = 32; o; o >>= 1) sum += __shfl_xor(sum, o);
    const float inv = 1.0f / sum;

    #pragma unroll
    for (int c = 0; c < 4; ++c) {
        const int k0 = c * 512 + lane * 8;
        if (k0 < rup) {
            union { short h[8]; bf16x8 v8; } o;
            #pragma unroll
            for (int j = 0; j < 8; ++j) {
                bf16 hh = __float2bfloat16(vals[c][j] * inv);
                o.h[j] = *(short*)&hh;
            }
            *(bf16x8*)(row + k0) = o.v8;
        }
    }
}

extern "C" void kernel_launch(void* const* d_in, const int* in_sizes, int n_in,
                              void* d_out, int out_size, void* d_ws, size_t ws_size,
                              hipStream_t stream)
{
    const float* v  = (const float*)d_in[0];
    const float* k  = (const float*)d_in[1];
    const float* q  = (const float*)d_in[2];
    const float* wi = (const float*)d_in[3];
    float* out = (float*)d_out;

    char* ws = (char*)d_ws;
    const size_t WT_OFF   = 0;                       // 2 MB
    const size_t PROJ_OFF = WT_OFF + (2u << 20);     // 48 MB
    const size_t VPT_OFF  = PROJ_OFF + (size_t)24576 * 1024 * 2;   // 16 MB
    const size_t XB_OFF   = VPT_OFF + (size_t)4 * 1024 * 2048 * 2; // 48 MB

    bf16* Wt   = (bf16*)(ws + WT_OFF);
    bf16* proj = (bf16*)(ws + PROJ_OFF);   // [q(8192)|k(8192)|v(8192)] x 1024
    bf16* vpT  = (bf16*)(ws + VPT_OFF);    // [4][1024][2048]
    bf16* Xb   = (bf16*)(ws + XB_OFF);     // [24576][1024] bf16 X
    bf16* P    = Xb;                       // P [4][2048][2048] aliases Xb (dead)

    bf16* qp_b = proj;
    bf16* kp_b = proj + (size_t)8192 * 1024;
    bf16* vp_b = proj + (size_t)16384 * 1024;

    (void)hipFuncSetAttribute((const void*)proj_2ph,
            hipFuncAttributeMaxDynamicSharedMemorySize, 131072);
    (void)hipFuncSetAttribute((const void*)scores128,
            hipFuncAttributeMaxDynamicSharedMemorySize, 81920);
    (void)hipFuncSetAttribute((const void*)pv128,
            hipFuncAttributeMaxDynamicSharedMemorySize, 81920);

    // merged wi-transpose + qkv convert
    convert_and_wi<<<3072, 256, 0, stream>>>(q, k, v, wi, Xb, Wt);

    // projection: 768 blocks = 3 exact rounds; 2-phase 16-MFMA pipeline
    proj_2ph<<<dim3(8, 96), 512, 131072, stream>>>(Xb, Wt, proj);

    transpose_vp<<<dim3(32, 64, 4), 256, 0, stream>>>(vp_b, vpT);

    // scores: triangular 136 tiles/batch, 128x128, 2 blocks/CU
    scores128<<<dim3(136, 1, 4), 256, 81920, stream>>>(qp_b, kp_b, P);

    softmax_rows<<<dim3(512, 4), 256, 0, stream>>>(P);

    // PV: 512 balanced single tiles, 2 blocks/CU
    pv128<<<dim3(512), 256, 81920, stream>>>(P, vpT, qp_b, out);
}

// Round 11
// 173.875 us; speedup vs baseline: 1.0735x; 1.0299x over previous
//
#include <hip/hip_runtime.h>
#include <hip/hip_bf16.h>

typedef __hip_bfloat16 bf16;
typedef short bf16x8 __attribute__((ext_vector_type(8)));
typedef float f32x4 __attribute__((ext_vector_type(4)));

#define HT 16384   // bf16 half-tile bytes: 128 rows x 64 cols

__device__ __forceinline__ void gload16(const void* g, void* l) {
    __builtin_amdgcn_global_load_lds(
        (const __attribute__((address_space(1))) void*)g,
        (__attribute__((address_space(3))) void*)l, 16, 0, 0);
}

// 512-thread staging of one 128x64 half-tile (2 gload16/thread)
__device__ __forceinline__ void stage_half(char* lds, const bf16* src, int ld,
                                           int rowbase, int k0, int slotIdx,
                                           int tid)
{
    char* dst = lds + (size_t)slotIdx * HT + tid * 16;
    const int sub = tid >> 3;
    const int cb  = ((tid & 7) ^ (sub & 7)) << 4;
    #pragma unroll
    for (int p = 0; p < 2; ++p) {
        const int row = p * 64 + sub;
        const char* g = (const char*)(src + (size_t)(rowbase + row) * ld + k0) + cb;
        gload16(g, dst + p * 8192);
    }
}

// 256-thread staging of one 128x64 half-tile (4 gload16/thread)
__device__ __forceinline__ void stage_q(char* lds, const bf16* src, int ld,
                                        int rowbase, int k0, int slotIdx,
                                        int tid)
{
    char* dst = lds + (size_t)slotIdx * HT + tid * 16;
    #pragma unroll
    for (int p = 0; p < 4; ++p) {
        const int s = p * 256 + tid;
        const int row = s >> 3;
        const int cb = ((s & 7) ^ (row & 7)) << 4;
        const char* g = (const char*)(src + (size_t)(rowbase + row) * ld + k0) + cb;
        gload16(g, dst + p * 4096);
    }
}

// read one MFMA A/B fragment (8 bf16 = 16B) with the read-side swizzle
__device__ __forceinline__ bf16x8 ldsfrag(const char* lds, int slotIdx,
                                          int row, int ks, int cb0)
{
    return *(const bf16x8*)(lds + (size_t)slotIdx * HT
                            + row * 128 + (cb0 ^ (ks << 6)));
}

__device__ __forceinline__ float bf2f(short s) {
    union { float f; unsigned u; } c;
    c.u = ((unsigned)(unsigned short)s) << 16;
    return c.f;
}

// ====== generic K=1024 GEMM: BM=256 BN=128, 8 waves 4Mx2N, 128 KiB ======
// MODE 0: Cb = bf16(A@B^T).  MODE 2: Cf = f32(A@B^T).
// lda = ldb = ldc = 1024 for all uses. XCD-chunked bijective swizzle.
template<int MODE>
__launch_bounds__(512, 2)
__global__ void gemm_a256(const bf16* __restrict__ A, const bf16* __restrict__ B,
                          bf16* __restrict__ Cb, float* __restrict__ Cf)
{
    extern __shared__ char lds[];
    const int gx = gridDim.x;
    const int nwg = gx * gridDim.y;
    const int chunk = nwg >> 3;
    const int orig = blockIdx.y * gx + blockIdx.x;
    const int wk2 = (orig & 7) * chunk + (orig >> 3);
    const int bi = wk2 / gx, bj = wk2 % gx;
    const int brow = bi * 256, bcol = bj * 128;

    const int tid  = threadIdx.x;
    const int lane = tid & 63;
    const int w    = tid >> 6;
    const int wm   = w >> 1, wn = w & 1;               // 4M x 2N, wave 64x64
    const int fr   = lane & 15, fq = lane >> 4;
    const int cb0  = ((fr & 7) ^ fq) << 4;
    const int hA   = wm >> 1;
    const int rA   = (wm & 1) * 64;
    const int rB   = wn * 64;
    const int NT   = 16;                               // K=1024/64

    f32x4 acc[4][4] = {};
    bf16x8 af[4][2], bv[4][2];

    // prologue: A(0)->slots 0,1; B(0)->6; A(1)->2,3; B(1)->7
    stage_half(lds, A, 1024, brow,       0, 0, tid);
    stage_half(lds, A, 1024, brow + 128, 0, 1, tid);
    stage_half(lds, B, 1024, bcol,       0, 6, tid);
    stage_half(lds, A, 1024, brow,      64, 2, tid);
    stage_half(lds, A, 1024, brow + 128,64, 3, tid);
    stage_half(lds, B, 1024, bcol,     64, 7, tid);
    asm volatile("s_waitcnt vmcnt(6)" ::: "memory");
    __builtin_amdgcn_s_barrier();

#define MF8(n0)                                                               \
    _Pragma("unroll") for (int m = 0; m < 4; ++m)                             \
    _Pragma("unroll") for (int dn = 0; dn < 2; ++dn)                          \
    _Pragma("unroll") for (int ks = 0; ks < 2; ++ks)                          \
        acc[m][(n0)+dn] = __builtin_amdgcn_mfma_f32_16x16x32_bf16(            \
            af[m][ks], bv[(n0)+dn][ks], acc[m][(n0)+dn], 0, 0, 0);

    for (int t = 0; t < NT; ++t) {
        const int aslot = (t % 3) * 2 + hA;
        const int bslot = 6 + (t & 1);
        const int a2    = ((t + 2) % 3) * 2;
        const int k2    = min(t + 2, NT - 1) << 6;

        // ph0: read all 16 frags; stage A(t+2)
        #pragma unroll
        for (int m = 0; m < 4; ++m)
            #pragma unroll
            for (int ks = 0; ks < 2; ++ks)
                af[m][ks] = ldsfrag(lds, aslot, rA + m * 16 + fr, ks, cb0);
        #pragma unroll
        for (int n = 0; n < 4; ++n)
            #pragma unroll
            for (int ks = 0; ks < 2; ++ks)
                bv[n][ks] = ldsfrag(lds, bslot, rB + n * 16 + fr, ks, cb0);
        stage_half(lds, A, 1024, brow,       k2, a2,     tid);
        stage_half(lds, A, 1024, brow + 128, k2, a2 + 1, tid);
        __builtin_amdgcn_s_barrier();
        __builtin_amdgcn_s_setprio(1);
        MF8(0)
        __builtin_amdgcn_s_setprio(0);
        __builtin_amdgcn_s_barrier();

        // ph1: stage B(t+2)
        stage_half(lds, B, 1024, bcol, k2, bslot, tid);
        __builtin_amdgcn_s_barrier();
        __builtin_amdgcn_s_setprio(1);
        MF8(2)
        __builtin_amdgcn_s_setprio(0);
        asm volatile("s_waitcnt vmcnt(6)" ::: "memory");
        __builtin_amdgcn_s_barrier();
    }
#undef MF8

    #pragma unroll
    for (int mf = 0; mf < 4; ++mf) {
        const int r0 = brow + wm * 64 + mf * 16 + fq * 4;
        #pragma unroll
        for (int nf = 0; nf < 4; ++nf) {
            const int c = bcol + wn * 64 + nf * 16 + fr;
            #pragma unroll
            for (int j = 0; j < 4; ++j) {
                if (MODE == 0)
                    Cb[(size_t)(r0 + j) * 1024 + c] =
                        __float2bfloat16(acc[mf][nf][j]);
                else
                    Cf[(size_t)(r0 + j) * 1024 + c] = acc[mf][nf][j];
            }
        }
    }
}

// ====== engine: 256 thr, 4 waves 2Mx2N (wave 64x64), block 128x128 ======
// LDS: A slots 0,1,2 (3-rot) + B slots 3,4 (dbuf) = 80 KiB -> 2 blocks/CU.
// MODE 1: Cb = bf16(scale * A@B^T).  MODE 2: Cb = bf16(A@B^T + Rf_f32).
template<int MODE>
__device__ __forceinline__ void tile128v2(char* lds, const bf16* A, const bf16* B,
                                          bf16* Cb, const float* Rf,
                                          int lda, int ldb, int ldcb,
                                          int brow, int bcol, int NT, float scale,
                                          int tid)
{
    const int lane = tid & 63;
    const int w    = tid >> 6;            // 0..3
    const int wm   = w >> 1, wn = w & 1;
    const int fr   = lane & 15, fq = lane >> 4;
    const int cb0  = ((fr & 7) ^ fq) << 4;

    f32x4 acc[4][4] = {};
    bf16x8 af[4][2], bv[4][2];

    stage_q(lds, A, lda, brow, 0,  0, tid);
    stage_q(lds, B, ldb, bcol, 0,  3, tid);
    stage_q(lds, A, lda, brow, 64, 1, tid);
    stage_q(lds, B, ldb, bcol, 64, 4, tid);
    asm volatile("s_waitcnt vmcnt(8)" ::: "memory");
    __builtin_amdgcn_s_barrier();

    for (int t = 0; t < NT; ++t) {
        const int aslot = t % 3, bslot = 3 + (t & 1);
        const int k2 = min(t + 2, NT - 1) << 6;

        // ph0: read all 16 frags; stage A(t+2)
        #pragma unroll
        for (int m = 0; m < 4; ++m)
            #pragma unroll
            for (int ks = 0; ks < 2; ++ks)
                af[m][ks] = ldsfrag(lds, aslot, wm * 64 + m * 16 + fr, ks, cb0);
        #pragma unroll
        for (int n = 0; n < 4; ++n)
            #pragma unroll
            for (int ks = 0; ks < 2; ++ks)
                bv[n][ks] = ldsfrag(lds, bslot, wn * 64 + n * 16 + fr, ks, cb0);
        stage_q(lds, A, lda, brow, k2, (t + 2) % 3, tid);
        __builtin_amdgcn_s_barrier();
        __builtin_amdgcn_s_setprio(1);
        #pragma unroll
        for (int m = 0; m < 4; ++m)
            #pragma unroll
            for (int n = 0; n < 2; ++n)
                #pragma unroll
                for (int ks = 0; ks < 2; ++ks)
                    acc[m][n] = __builtin_amdgcn_mfma_f32_16x16x32_bf16(
                        af[m][ks], bv[n][ks], acc[m][n], 0, 0, 0);
        __builtin_amdgcn_s_setprio(0);
        __builtin_amdgcn_s_barrier();

        // ph1: stage B(t+2) (bv fully read in ph0)
        stage_q(lds, B, ldb, bcol, k2, bslot, tid);
        __builtin_amdgcn_s_barrier();
        __builtin_amdgcn_s_setprio(1);
        #pragma unroll
        for (int m = 0; m < 4; ++m)
            #pragma unroll
            for (int n = 2; n < 4; ++n)
                #pragma unroll
                for (int ks = 0; ks < 2; ++ks)
                    acc[m][n] = __builtin_amdgcn_mfma_f32_16x16x32_bf16(
                        af[m][ks], bv[n][ks], acc[m][n], 0, 0, 0);
        __builtin_amdgcn_s_setprio(0);
        asm volatile("s_waitcnt vmcnt(8)" ::: "memory");
        __builtin_amdgcn_s_barrier();
    }

    #pragma unroll
    for (int mf = 0; mf < 4; ++mf) {
        const int r0 = brow + wm * 64 + mf * 16 + fq * 4;
        #pragma unroll
        for (int nf = 0; nf < 4; ++nf) {
            const int c = bcol + wn * 64 + nf * 16 + fr;
            #pragma unroll
            for (int j = 0; j < 4; ++j) {
                if (MODE == 1)
                    Cb[(size_t)(r0 + j) * ldcb + c] =
                        __float2bfloat16(acc[mf][nf][j] * scale);
                else
                    Cb[(size_t)(r0 + j) * ldcb + c] = __float2bfloat16(
                        acc[mf][nf][j] + Rf[(size_t)(r0 + j) * ldcb + c]);
            }
        }
    }
}

// scores: triangular grid, per batch 136 tiles of 128x128; P = qG@k^T * 1/32
__launch_bounds__(256, 2)
__global__ void scores128(const bf16* __restrict__ qG, const bf16* __restrict__ kb,
                          bf16* __restrict__ P)
{
    extern __shared__ char lds[];
    const int j = blockIdx.x;                     // 0..135
    int bi = (int)((__fsqrt_rn(8.0f * j + 1.0f) - 1.0f) * 0.5f);
    while ((bi + 1) * (bi + 2) / 2 <= j) ++bi;
    while (bi * (bi + 1) / 2 > j) --bi;
    const int bj = j - bi * (bi + 1) / 2;         // bj <= bi
    const int bz = blockIdx.z;

    tile128v2<1>(lds,
                 qG + (size_t)bz * 2048 * 1024,
                 kb + (size_t)bz * 2048 * 1024,
                 P + (size_t)bz * 2048 * 2048, nullptr,
                 1024, 1024, 2048,
                 bi * 128, bj * 128, 16, 0.03125f, threadIdx.x);
}

// PV: Y = attn@v + q (f32 residual), bf16 out. 512 balanced single tiles.
__launch_bounds__(256, 2)
__global__ void pv128(const bf16* __restrict__ P, const bf16* __restrict__ vT,
                      const float* __restrict__ q, bf16* __restrict__ Y)
{
    extern __shared__ char lds[];
    const int x  = blockIdx.x;                // 0..511
    const int u  = x & 255;
    const int bs = u & 7;
    const int bj = (u >> 3) & 7;
    const int bz = u >> 6;
    const int bi = (x >> 8) ? (15 - bs) : bs;

    tile128v2<2>(lds,
                 P + (size_t)bz * 2048 * 2048,
                 vT + (size_t)bz * 1024 * 2048,
                 Y + (size_t)bz * 2048 * 1024,
                 q + (size_t)bz * 2048 * 1024,
                 2048, 2048, 1024,
                 bi * 128, bj * 128, 2 * (bi + 1), 1.0f, threadIdx.x);
}

// convert q,k -> bf16 [8192][1024]; wi -> Wb bf16 [1024][1024] (row-major)
__global__ void convert_qk_w(const float* __restrict__ q, const float* __restrict__ k,
                             const float* __restrict__ wi,
                             bf16* __restrict__ qb, bf16* __restrict__ kb,
                             bf16* __restrict__ Wb)
{
    const int N8 = 8192 * 1024 / 8;
    const int W8 = 1024 * 1024 / 8;
    const int total = 2 * N8 + W8;
    for (int i = blockIdx.x * 256 + threadIdx.x; i < total; i += gridDim.x * 256) {
        const float4* s;
        bf16* dst;
        int j;
        if (i < N8)            { s = (const float4*)q;  dst = qb; j = i; }
        else if (i < 2 * N8)   { s = (const float4*)k;  dst = kb; j = i - N8; }
        else                   { s = (const float4*)wi; dst = Wb; j = i - 2 * N8; }
        float4 a = s[2 * j], b = s[2 * j + 1];
        float vals[8] = {a.x, a.y, a.z, a.w, b.x, b.y, b.z, b.w};
        union { short h[8]; bf16x8 v8; } o;
        #pragma unroll
        for (int e = 0; e < 8; ++e) {
            bf16 hh = __float2bfloat16(vals[e]);
            o.h[e] = *(short*)&hh;
        }
        ((bf16x8*)dst)[j] = o.v8;
    }
}

// z<4: vT[z][d][s] = bf16(v[z][s][d]);  z==4 (y<32): Wt[n][k] = bf16(wi[k][n])
__global__ void transpose_vwi(const float* __restrict__ v,
                              const float* __restrict__ wi,
                              bf16* __restrict__ vT, bf16* __restrict__ Wt)
{
    __shared__ float t[32][33];
    const int z = blockIdx.z;
    const int lx = threadIdx.x & 31, ly = threadIdx.x >> 5;
    if (z < 4) {
        const int d0 = blockIdx.x * 32, s0 = blockIdx.y * 32;
        const float* src = v + (size_t)z * 2048 * 1024;
        bf16* dst = vT + (size_t)z * 1024 * 2048;
        for (int i = ly; i < 32; i += 8)
            t[i][lx] = src[(size_t)(s0 + i) * 1024 + d0 + lx];
        __syncthreads();
        for (int i = ly; i < 32; i += 8)
            dst[(size_t)(d0 + i) * 2048 + s0 + lx] = __float2bfloat16(t[lx][i]);
    } else {
        if (blockIdx.y >= 32) return;
        const int n0 = blockIdx.x * 32, k0 = blockIdx.y * 32;
        for (int i = ly; i < 32; i += 8)
            t[i][lx] = wi[(size_t)(k0 + i) * 1024 + n0 + lx];
        __syncthreads();
        for (int i = ly; i < 32; i += 8)
            Wt[(size_t)(n0 + i) * 1024 + k0 + lx] = __float2bfloat16(t[lx][i]);
    }
}

// wave-per-row causal softmax, zero-fill to 128-aligned boundary
__launch_bounds__(256)
__global__ void softmax_rows(bf16* __restrict__ P)
{
    const int wid = threadIdx.x >> 6, lane = threadIdx.x & 63;
    const int r = blockIdx.x * 4 + wid, b = blockIdx.y;
    bf16* row = P + ((size_t)b * 2048 + r) * 2048;
    const int nv  = r + 1;
    const int rup = (r & ~127) + 128;

    float vals[4][8];
    float m = -1e30f;
    #pragma unroll
    for (int c = 0; c < 4; ++c) {
        const int k0 = c * 512 + lane * 8;
        if (k0 < rup) {
            bf16x8 x = *(const bf16x8*)(row + k0);
            #pragma unroll
            for (int j = 0; j < 8; ++j) {
                float f = (k0 + j < nv) ? bf2f(x[j]) : -1e30f;
                vals[c][j] = f;
                m = fmaxf(m, f);
            }
        } else {
            #pragma unroll
            for (int j = 0; j < 8; ++j) vals[c][j] = -1e30f;
        }
    }
    #pragma unroll
    for (int o = 32; o; o >>= 1) m = fmaxf(m, __shfl_xor(m, o));

    float sum = 0.f;
    #pragma unroll
    for (int c = 0; c < 4; ++c)
        #pragma unroll
        for (int j = 0; j < 8; ++j) {
            float e = __expf(vals[c][j] - m);
            vals[c][j] = e;
            sum += e;
        }
    #pragma unroll
    for (int o = 32; o; o >>= 1) sum += __shfl_xor(sum, o);
    const float inv = 1.0f / sum;

    #pragma unroll
    for (int c = 0; c < 4; ++c) {
        const int k0 = c * 512 + lane * 8;
        if (k0 < rup) {
            union { short h[8]; bf16x8 v8; } o;
            #pragma unroll
            for (int j = 0; j < 8; ++j) {
                bf16 hh = __float2bfloat16(vals[c][j] * inv);
                o.h[j] = *(short*)&hh;
            }
            *(bf16x8*)(row + k0) = o.v8;
        }
    }
}

extern "C" void kernel_launch(void* const* d_in, const int* in_sizes, int n_in,
                              void* d_out, int out_size, void* d_ws, size_t ws_size,
                              hipStream_t stream)
{
    const float* v  = (const float*)d_in[0];
    const float* k  = (const float*)d_in[1];
    const float* q  = (const float*)d_in[2];
    const float* wi = (const float*)d_in[3];
    float* out = (float*)d_out;

    char* ws = (char*)d_ws;
    const size_t MB = 1u << 20;
    bf16* Wb = (bf16*)(ws);                 // [1024][1024] W row-major
    bf16* Wt = (bf16*)(ws + 2 * MB);        // [1024][1024] W^T
    bf16* G  = (bf16*)(ws + 4 * MB);        // [1024][1024] W@W^T (symmetric)
    bf16* qb = (bf16*)(ws + 6 * MB);        // [8192][1024]
    bf16* kb = (bf16*)(ws + 22 * MB);       // [8192][1024]
    bf16* vT = (bf16*)(ws + 38 * MB);       // [4][1024][2048]
    bf16* qG = (bf16*)(ws + 54 * MB);       // [8192][1024]
    bf16* Y  = (bf16*)(ws + 70 * MB);       // [8192][1024]  q + attn@v
    bf16* P  = (bf16*)(ws + 86 * MB);       // [4][2048][2048]

    (void)hipFuncSetAttribute((const void*)gemm_a256<0>,
            hipFuncAttributeMaxDynamicSharedMemorySize, 131072);
    (void)hipFuncSetAttribute((const void*)gemm_a256<2>,
            hipFuncAttributeMaxDynamicSharedMemorySize, 131072);
    (void)hipFuncSetAttribute((const void*)scores128,
            hipFuncAttributeMaxDynamicSharedMemorySize, 81920);
    (void)hipFuncSetAttribute((const void*)pv128,
            hipFuncAttributeMaxDynamicSharedMemorySize, 81920);

    convert_qk_w<<<2048, 256, 0, stream>>>(q, k, wi, qb, kb, Wb);
    transpose_vwi<<<dim3(32, 64, 5), 256, 0, stream>>>(v, wi, vT, Wt);

    // G = W @ W^T  (1024x1024, 32 blocks)
    gemm_a256<0><<<dim3(8, 4), 512, 131072, stream>>>(Wb, Wb, G, nullptr);

    // qG = q @ G   (8192x1024, 256 blocks = exactly 1 round)
    gemm_a256<0><<<dim3(8, 32), 512, 131072, stream>>>(qb, G, qG, nullptr);

    // scores: P = qG @ k^T * 1/32, causal triangular tiles
    scores128<<<dim3(136, 1, 4), 256, 81920, stream>>>(qG, kb, P);

    softmax_rows<<<dim3(512, 4), 256, 0, stream>>>(P);

    // Y = attn @ v + q   (bf16 out, f32 residual)
    pv128<<<dim3(512), 256, 81920, stream>>>(P, vT, q, Y);

    // out = Y @ W  (f32, 256 blocks = exactly 1 round)
    gemm_a256<2><<<dim3(8, 32), 512, 131072, stream>>>(Y, Wt, nullptr, out);
}